// Round 2
// baseline (979.177 us; speedup 1.0000x reference)
//
#include <hip/hip_runtime.h>

#define F 16
#define BSHIFT 6
#define NPB 64            // nodes per bucket = 1<<BSHIFT
#define NB 1563           // buckets for N=100000: (100000+63)>>6

// ========================= fast path kernels ================================

// block-privatized histogram of dst>>6 into bcount[NB]
__global__ void hist_kernel(const int* __restrict__ dst, unsigned* __restrict__ bcount, int E) {
    __shared__ unsigned lc[NB];
    for (int i = threadIdx.x; i < NB; i += blockDim.x) lc[i] = 0;
    __syncthreads();
    int stride = gridDim.x * blockDim.x;
    for (int e = blockIdx.x * blockDim.x + threadIdx.x; e < E; e += stride)
        atomicAdd(&lc[((unsigned)dst[e]) >> BSHIFT], 1u);
    __syncthreads();
    for (int i = threadIdx.x; i < NB; i += blockDim.x) {
        unsigned c = lc[i];
        if (c) atomicAdd(&bcount[i], c);
    }
}

// single-block exclusive scan of NB counts -> off[], cursor[] (cursor padded x16)
__global__ void scan_kernel(const unsigned* __restrict__ bcount, int* __restrict__ off,
                            unsigned* __restrict__ cursor, int E) {
    __shared__ unsigned s[2048];
    int t = threadIdx.x; // 1024 threads
    unsigned c0 = (t < NB) ? bcount[t] : 0u;
    unsigned c1 = (t + 1024 < NB) ? bcount[t + 1024] : 0u;
    s[t] = c0; s[t + 1024] = c1;
    __syncthreads();
    for (int d = 1; d < 2048; d <<= 1) {
        unsigned a  = (t >= d) ? s[t - d] : 0u;
        unsigned bv = (t + 1024 >= d) ? s[t + 1024 - d] : 0u;
        __syncthreads();
        s[t] += a; s[t + 1024] += bv;
        __syncthreads();
    }
    if (t < NB)       { unsigned ex = s[t] - c0;       off[t] = ex;       cursor[t * 16] = ex; }
    if (t + 1024 < NB){ unsigned ex = s[t+1024] - c1;  off[t+1024] = ex;  cursor[(t+1024)*16] = ex; }
    if (t == 0) off[NB] = E;
}

// scatter edges into bucket-sorted rec array: rec = src | (dst&63)<<17
__global__ void reorder_kernel(const int* __restrict__ src, const int* __restrict__ dst,
                               unsigned* __restrict__ cursor, unsigned* __restrict__ recs, int E) {
    int e = blockIdx.x * blockDim.x + threadIdx.x;
    if (e < E) {
        unsigned d = (unsigned)dst[e];
        unsigned b = d >> BSHIFT;
        unsigned pos = atomicAdd(&cursor[b * 16], 1u);
        recs[pos] = (unsigned)src[e] | ((d & (NPB - 1u)) << 17);
    }
}

// per-bucket degree via LDS counters -> dinv = rsqrt(deg+1)
__global__ void degdinv_kernel(const unsigned* __restrict__ recs, const int* __restrict__ off,
                               float* __restrict__ dinv, int n) {
    __shared__ unsigned cnt[NPB];
    int t = threadIdx.x, b = blockIdx.x;
    if (t < NPB) cnt[t] = 0;
    __syncthreads();
    int e1 = off[b + 1];
    for (int e = off[b] + t; e < e1; e += 256) atomicAdd(&cnt[recs[e] >> 17], 1u);
    __syncthreads();
    if (t < NPB) {
        int node = b * NPB + t;
        if (node < n) dinv[node] = rsqrtf((float)cnt[t] + 1.0f);
    }
}

// h[i,:] = (x[i,:] @ W) * dinv[i]    (16 nodes/block, 16 feats/node)
__global__ void linear_kernel(const float* __restrict__ in, const float* __restrict__ dinv,
                              const float* __restrict__ W, float* __restrict__ out, int n) {
    __shared__ float Ws[F * F];
    __shared__ float As[16][F + 1];
    int t = threadIdx.x;
    Ws[t] = W[t];
    int nb = t >> 4, j = t & 15;
    int i = blockIdx.x * 16 + nb;
    float di = 0.f, v = 0.f;
    if (i < n) { di = dinv[i]; v = in[i * F + j]; }
    As[nb][j] = v;
    __syncthreads();
    if (i < n) {
        float s = 0.f;
#pragma unroll
        for (int k = 0; k < F; ++k) s += As[nb][k] * Ws[k * F + j];
        out[i * F + j] = s * di;
    }
}

// bucketed gather-aggregation + fused epilogue.
// mode 1: a = relu(dinv*(acc+hin_self)+bias); out = (a @ Wn) * dinv   (mid layer)
// mode 2: out = dinv*(acc+hin_self)+bias                              (final)
__global__ void agg_kernel(const float* __restrict__ hin, const unsigned* __restrict__ recs,
                           const int* __restrict__ off, const float* __restrict__ dinv,
                           const float* __restrict__ Wn, const float* __restrict__ bias,
                           float* __restrict__ outp, int n, int mode) {
    __shared__ float acc[NPB * 17];
    __shared__ float a1[NPB * 17];
    __shared__ float Ws[F * F];
    int t = threadIdx.x, b = blockIdx.x;
    for (int i = t; i < NPB * 17; i += 256) acc[i] = 0.f;
    if (mode == 1) Ws[t] = Wn[t];
    __syncthreads();
    int j = t & 15, g = t >> 4;
    int e1 = off[b + 1];
#pragma unroll 2
    for (int e = off[b] + g; e < e1; e += 16) {
        unsigned rec = recs[e];
        int s  = rec & 0x1FFFF;
        int ld = rec >> 17;
        float v = hin[s * F + j];
        atomicAdd(&acc[ld * 17 + j], v);
    }
    __syncthreads();
    int base = b * NPB;
    if (mode == 1) {
        for (int q = 0; q < 4; ++q) {
            int r = q * 16 + g, node = base + r;
            if (node < n) {
                float di = dinv[node];
                float v = di * (acc[r * 17 + j] + hin[node * F + j]) + bias[j];
                a1[r * 17 + j] = fmaxf(v, 0.f);
            }
        }
        __syncthreads();
        for (int q = 0; q < 4; ++q) {
            int r = q * 16 + g, node = base + r;
            if (node < n) {
                float di = dinv[node];
                float s2 = 0.f;
#pragma unroll
                for (int k = 0; k < F; ++k) s2 += a1[r * 17 + k] * Ws[k * F + j];
                outp[node * F + j] = s2 * di;
            }
        }
    } else {
        for (int q = 0; q < 4; ++q) {
            int r = q * 16 + g, node = base + r;
            if (node < n) {
                float di = dinv[node];
                outp[node * F + j] = di * (acc[r * 17 + j] + hin[node * F + j]) + bias[j];
            }
        }
    }
}

// ========================= fallback (R1) kernels ============================

__global__ void deg_kernel(const int* __restrict__ dst, float* __restrict__ deg, int E) {
    int e = blockIdx.x * blockDim.x + threadIdx.x;
    if (e < E) atomicAdd(&deg[dst[e]], 1.0f);
}
__global__ void dinv_kernel(float* __restrict__ deg, int n) {
    int i = blockIdx.x * blockDim.x + threadIdx.x;
    if (i < n) deg[i] = rsqrtf(deg[i] + 1.0f);
}
__global__ void linear2_kernel(const float* __restrict__ in, const float* __restrict__ acc,
                               const float* __restrict__ dinv, const float* __restrict__ W,
                               const float* __restrict__ bias, float* __restrict__ out,
                               int n, int mode) {
    __shared__ float Ws[F * F];
    __shared__ float As[16][F + 1];
    int t = threadIdx.x;
    Ws[t] = W[t];
    int nb = t >> 4, j = t & 15;
    int i = blockIdx.x * 16 + nb;
    float di = 0.f, v = 0.f;
    if (i < n) {
        di = dinv[i]; v = in[i * F + j];
        if (mode) { v = di * (acc[i * F + j] + v) + bias[j]; v = fmaxf(v, 0.f); }
    }
    As[nb][j] = v;
    __syncthreads();
    if (i < n) {
        float s = 0.f;
#pragma unroll
        for (int k = 0; k < F; ++k) s += As[nb][k] * Ws[k * F + j];
        out[i * F + j] = s * di;
    }
}
__global__ void scatter_kernel(const int* __restrict__ src, const int* __restrict__ dst,
                               const float* __restrict__ h, float* __restrict__ acc, int E) {
    int t = blockIdx.x * blockDim.x + threadIdx.x;
    int e = t >> 4, j = t & 15;
    if (e < E) atomicAdd(&acc[dst[e] * F + j], h[src[e] * F + j]);
}
__global__ void out_kernel(const float* __restrict__ acc, const float* __restrict__ h,
                           const float* __restrict__ dinv, const float* __restrict__ bias,
                           float* __restrict__ out, int n) {
    int t = blockIdx.x * blockDim.x + threadIdx.x;
    if (t < n * F) {
        int i = t >> 4, j = t & 15;
        out[t] = dinv[i] * (acc[t] + h[t]) + bias[j];
    }
}

// ========================= launch ===========================================

extern "C" void kernel_launch(void* const* d_in, const int* in_sizes, int n_in,
                              void* d_out, int out_size, void* d_ws, size_t ws_size,
                              hipStream_t stream) {
    const float* x  = (const float*)d_in[0];
    const int*   ei = (const int*)d_in[1];
    const float* W1 = (const float*)d_in[2];
    const float* b1 = (const float*)d_in[3];
    const float* W2 = (const float*)d_in[4];
    const float* b2 = (const float*)d_in[5];
    float* outp = (float*)d_out;

    const int N = in_sizes[0] / F;
    const int E = in_sizes[1] / 2;
    const int* src = ei;
    const int* dst = ei + E;

    const int nb_rt = (N + NPB - 1) >> BSHIFT;
    // ws layout: dinv[N] | hA[16N] | hB[16N] | recs[E] | bcount[NB] | off[NB+1] | cursor[16*NB]
    size_t need = sizeof(float) * ((size_t)N * 33 + 0) + sizeof(unsigned) * ((size_t)E + NB + (NB + 1) + 16 * NB);

    if (nb_rt == NB && ws_size >= need) {
        float* dinv = (float*)d_ws;
        float* hA = dinv + N;
        float* hB = hA + (size_t)F * N;
        unsigned* recs = (unsigned*)(hB + (size_t)F * N);
        unsigned* bcount = recs + E;
        int* off = (int*)(bcount + NB);
        unsigned* cursor = (unsigned*)(off + NB + 1);

        hipMemsetAsync(bcount, 0, NB * sizeof(unsigned), stream);
        hist_kernel<<<128, 256, 0, stream>>>(dst, bcount, E);
        scan_kernel<<<1, 1024, 0, stream>>>(bcount, off, cursor, E);
        reorder_kernel<<<(E + 255) / 256, 256, 0, stream>>>(src, dst, cursor, recs, E);
        degdinv_kernel<<<NB, 256, 0, stream>>>(recs, off, dinv, N);
        linear_kernel<<<(N + 15) / 16, 256, 0, stream>>>(x, dinv, W1, hA, N);
        agg_kernel<<<NB, 256, 0, stream>>>(hA, recs, off, dinv, W2, b1, hB, N, 1);
        agg_kernel<<<NB, 256, 0, stream>>>(hB, recs, off, dinv, nullptr, b2, outp, N, 2);
    } else {
        // R1 fallback: atomic scatter path (13.2MB ws)
        float* dinv = (float*)d_ws;
        float* h = dinv + N;
        float* acc = h + (size_t)F * N;
        hipMemsetAsync(dinv, 0, (size_t)N * sizeof(float), stream);
        hipMemsetAsync(acc, 0, (size_t)F * N * sizeof(float), stream);
        deg_kernel<<<(E + 255) / 256, 256, 0, stream>>>(dst, dinv, E);
        dinv_kernel<<<(N + 255) / 256, 256, 0, stream>>>(dinv, N);
        linear2_kernel<<<(N + 15) / 16, 256, 0, stream>>>(x, nullptr, dinv, W1, nullptr, h, N, 0);
        scatter_kernel<<<((size_t)E * F + 255) / 256, 256, 0, stream>>>(src, dst, h, acc, E);
        linear2_kernel<<<(N + 15) / 16, 256, 0, stream>>>(h, acc, dinv, W2, b1, h, N, 1);
        hipMemsetAsync(acc, 0, (size_t)F * N * sizeof(float), stream);
        scatter_kernel<<<((size_t)E * F + 255) / 256, 256, 0, stream>>>(src, dst, h, acc, E);
        out_kernel<<<((size_t)N * F + 255) / 256, 256, 0, stream>>>(acc, h, dinv, b2, outp, N);
    }
}

// Round 3
// 449.120 us; speedup vs baseline: 2.1802x; 2.1802x over previous
//
#include <hip/hip_runtime.h>

#define F 16
#define BSHIFT 6
#define NPB 64            // nodes per bucket = 1<<BSHIFT
#define NB 1563           // buckets for N=100000: (100000+63)>>6

// ========================= fast path kernels ================================

// block-privatized histogram of dst>>6 into bcount[NB]
__global__ void hist_kernel(const int* __restrict__ dst, unsigned* __restrict__ bcount, int E) {
    __shared__ unsigned lc[NB];
    for (int i = threadIdx.x; i < NB; i += blockDim.x) lc[i] = 0;
    __syncthreads();
    int stride = gridDim.x * blockDim.x;
    for (int e = blockIdx.x * blockDim.x + threadIdx.x; e < E; e += stride)
        atomicAdd(&lc[((unsigned)dst[e]) >> BSHIFT], 1u);
    __syncthreads();
    for (int i = threadIdx.x; i < NB; i += blockDim.x) {
        unsigned c = lc[i];
        if (c) atomicAdd(&bcount[i], c);
    }
}

// single-block exclusive scan of NB counts -> off[], cursor[] (cursor padded x16)
__global__ void scan_kernel(const unsigned* __restrict__ bcount, int* __restrict__ off,
                            unsigned* __restrict__ cursor, int E) {
    __shared__ unsigned s[2048];
    int t = threadIdx.x; // 1024 threads
    unsigned c0 = (t < NB) ? bcount[t] : 0u;
    unsigned c1 = (t + 1024 < NB) ? bcount[t + 1024] : 0u;
    s[t] = c0; s[t + 1024] = c1;
    __syncthreads();
    for (int d = 1; d < 2048; d <<= 1) {
        unsigned a  = (t >= d) ? s[t - d] : 0u;
        unsigned bv = (t + 1024 >= d) ? s[t + 1024 - d] : 0u;
        __syncthreads();
        s[t] += a; s[t + 1024] += bv;
        __syncthreads();
    }
    if (t < NB)       { unsigned ex = s[t] - c0;       off[t] = ex;       cursor[t * 16] = ex; }
    if (t + 1024 < NB){ unsigned ex = s[t+1024] - c1;  off[t+1024] = ex;  cursor[(t+1024)*16] = ex; }
    if (t == 0) off[NB] = E;
}

// scatter edges into bucket-sorted rec array: rec = src | (dst&63)<<17
__global__ void reorder_kernel(const int* __restrict__ src, const int* __restrict__ dst,
                               unsigned* __restrict__ cursor, unsigned* __restrict__ recs, int E) {
    int e = blockIdx.x * blockDim.x + threadIdx.x;
    if (e < E) {
        unsigned d = (unsigned)dst[e];
        unsigned b = d >> BSHIFT;
        unsigned pos = atomicAdd(&cursor[b * 16], 1u);
        recs[pos] = (unsigned)src[e] | ((d & (NPB - 1u)) << 17);
    }
}

// per-bucket node-granularity sort: recs (bucket-sorted) -> srcs (dst-sorted),
// plus CSR offsets noff[] and dinv[] from the LDS degree histogram.
__global__ void sort2_kernel(const unsigned* __restrict__ recs, const int* __restrict__ off,
                             unsigned* __restrict__ srcs, int* __restrict__ noff,
                             float* __restrict__ dinv, int n, int E) {
    __shared__ unsigned cnt[NPB];
    __shared__ unsigned curs[NPB];
    int t = threadIdx.x, b = blockIdx.x;
    if (t < NPB) cnt[t] = 0;
    __syncthreads();
    int e0 = off[b], e1 = off[b + 1];
    for (int e = e0 + t; e < e1; e += 256) atomicAdd(&cnt[recs[e] >> 17], 1u);
    __syncthreads();
    if (t < NPB) {                       // wave 0: 64-wide exclusive scan
        unsigned c = cnt[t];
        unsigned inc = c;
#pragma unroll
        for (int d = 1; d < NPB; d <<= 1) {
            unsigned o = __shfl_up(inc, d, 64);
            if (t >= d) inc += o;
        }
        unsigned ex = inc - c;
        curs[t] = (unsigned)e0 + ex;
        int node = b * NPB + t;
        if (node < n) {
            noff[node] = e0 + ex;
            dinv[node] = rsqrtf((float)c + 1.0f);
        }
    }
    if (b == gridDim.x - 1 && t == 0) noff[n] = E;
    __syncthreads();
    for (int e = e0 + t; e < e1; e += 256) {
        unsigned rec = recs[e];
        unsigned pos = atomicAdd(&curs[rec >> 17], 1u);
        srcs[pos] = rec & 0x1FFFFu;
    }
}

// h[i,:] = (x[i,:] @ W) * dinv[i]    (16 nodes/block, 16 feats/node)
__global__ void linear_kernel(const float* __restrict__ in, const float* __restrict__ dinv,
                              const float* __restrict__ W, float* __restrict__ out, int n) {
    __shared__ float Ws[F * F];
    __shared__ float As[16][F + 1];
    int t = threadIdx.x;
    Ws[t] = W[t];
    int nb = t >> 4, j = t & 15;
    int i = blockIdx.x * 16 + nb;
    float di = 0.f, v = 0.f;
    if (i < n) { di = dinv[i]; v = in[i * F + j]; }
    As[nb][j] = v;
    __syncthreads();
    if (i < n) {
        float s = 0.f;
#pragma unroll
        for (int k = 0; k < F; ++k) s += As[nb][k] * Ws[k * F + j];
        out[i * F + j] = s * di;
    }
}

// atomic-free CSR aggregation, one 16-lane group per node, fused epilogue.
// s = sum over in-edges of hin[src,:]; v = dinv*(s + hin[node,:]) + bias
// mode 1: out = (relu(v) @ Wn) * dinv      (mid layer)
// mode 2: out = v                          (final layer)
__global__ void agg_csr_kernel(const float* __restrict__ hin, const unsigned* __restrict__ srcs,
                               const int* __restrict__ noff, const float* __restrict__ dinv,
                               const float* __restrict__ Wn, const float* __restrict__ bias,
                               float* __restrict__ outp, int n, int mode) {
    __shared__ float a1[16][F + 1];
    __shared__ float Ws[F * F];
    int t = threadIdx.x;
    int g = t >> 4, j = t & 15;
    if (mode == 1) Ws[t] = Wn[t];
    int node = blockIdx.x * 16 + g;
    float val = 0.f, di = 0.f;
    if (node < n) {
        di = dinv[node];
        int e0 = noff[node], e1 = noff[node + 1];
        float s0 = 0.f, s1 = 0.f, s2 = 0.f, s3 = 0.f;
        int e = e0;
        for (; e + 4 <= e1; e += 4) {
            int sa = srcs[e], sb = srcs[e + 1], sc = srcs[e + 2], sd = srcs[e + 3];
            s0 += hin[sa * F + j];
            s1 += hin[sb * F + j];
            s2 += hin[sc * F + j];
            s3 += hin[sd * F + j];
        }
        for (; e < e1; ++e) s0 += hin[srcs[e] * F + j];
        float s = (s0 + s1) + (s2 + s3);
        val = di * (s + hin[node * F + j]) + bias[j];
        if (mode == 1) val = fmaxf(val, 0.f);
    }
    if (mode == 1) {
        a1[g][j] = val;
        __syncthreads();
        if (node < n) {
            float s2 = 0.f;
#pragma unroll
            for (int k = 0; k < F; ++k) s2 += a1[g][k] * Ws[k * F + j];
            outp[node * F + j] = s2 * di;
        }
    } else {
        if (node < n) outp[node * F + j] = val;
    }
}

// ========================= fallback (R1) kernels ============================

__global__ void deg_kernel(const int* __restrict__ dst, float* __restrict__ deg, int E) {
    int e = blockIdx.x * blockDim.x + threadIdx.x;
    if (e < E) atomicAdd(&deg[dst[e]], 1.0f);
}
__global__ void dinv_kernel(float* __restrict__ deg, int n) {
    int i = blockIdx.x * blockDim.x + threadIdx.x;
    if (i < n) deg[i] = rsqrtf(deg[i] + 1.0f);
}
__global__ void linear2_kernel(const float* __restrict__ in, const float* __restrict__ acc,
                               const float* __restrict__ dinv, const float* __restrict__ W,
                               const float* __restrict__ bias, float* __restrict__ out,
                               int n, int mode) {
    __shared__ float Ws[F * F];
    __shared__ float As[16][F + 1];
    int t = threadIdx.x;
    Ws[t] = W[t];
    int nb = t >> 4, j = t & 15;
    int i = blockIdx.x * 16 + nb;
    float di = 0.f, v = 0.f;
    if (i < n) {
        di = dinv[i]; v = in[i * F + j];
        if (mode) { v = di * (acc[i * F + j] + v) + bias[j]; v = fmaxf(v, 0.f); }
    }
    As[nb][j] = v;
    __syncthreads();
    if (i < n) {
        float s = 0.f;
#pragma unroll
        for (int k = 0; k < F; ++k) s += As[nb][k] * Ws[k * F + j];
        out[i * F + j] = s * di;
    }
}
__global__ void scatter_kernel(const int* __restrict__ src, const int* __restrict__ dst,
                               const float* __restrict__ h, float* __restrict__ acc, int E) {
    int t = blockIdx.x * blockDim.x + threadIdx.x;
    int e = t >> 4, j = t & 15;
    if (e < E) atomicAdd(&acc[dst[e] * F + j], h[src[e] * F + j]);
}
__global__ void out_kernel(const float* __restrict__ acc, const float* __restrict__ h,
                           const float* __restrict__ dinv, const float* __restrict__ bias,
                           float* __restrict__ out, int n) {
    int t = blockIdx.x * blockDim.x + threadIdx.x;
    if (t < n * F) {
        int i = t >> 4, j = t & 15;
        out[t] = dinv[i] * (acc[t] + h[t]) + bias[j];
    }
}

// ========================= launch ===========================================

extern "C" void kernel_launch(void* const* d_in, const int* in_sizes, int n_in,
                              void* d_out, int out_size, void* d_ws, size_t ws_size,
                              hipStream_t stream) {
    const float* x  = (const float*)d_in[0];
    const int*   ei = (const int*)d_in[1];
    const float* W1 = (const float*)d_in[2];
    const float* b1 = (const float*)d_in[3];
    const float* W2 = (const float*)d_in[4];
    const float* b2 = (const float*)d_in[5];
    float* outp = (float*)d_out;

    const int N = in_sizes[0] / F;
    const int E = in_sizes[1] / 2;
    const int* src = ei;
    const int* dst = ei + E;

    const int nb_rt = (N + NPB - 1) >> BSHIFT;
    // ws layout (4B units): dinv[N] | hA[16N] | hB[16N] | recs[E] | srcs[E] |
    //                       noff[N+1] | bcount[NB] | off[NB+1] | cursor[16*NB]
    size_t need = sizeof(float) * ((size_t)N * 33 + (N + 1)
                                   + 2 * (size_t)E + NB + (NB + 1) + 16 * NB);

    if (nb_rt == NB && ws_size >= need) {
        float* dinv = (float*)d_ws;
        float* hA = dinv + N;
        float* hB = hA + (size_t)F * N;
        unsigned* recs = (unsigned*)(hB + (size_t)F * N);
        unsigned* srcs = recs + E;
        int* noff = (int*)(srcs + E);
        unsigned* bcount = (unsigned*)(noff + N + 1);
        int* off = (int*)(bcount + NB);
        unsigned* cursor = (unsigned*)(off + NB + 1);

        hipMemsetAsync(bcount, 0, NB * sizeof(unsigned), stream);
        hist_kernel<<<256, 256, 0, stream>>>(dst, bcount, E);
        scan_kernel<<<1, 1024, 0, stream>>>(bcount, off, cursor, E);
        reorder_kernel<<<(E + 255) / 256, 256, 0, stream>>>(src, dst, cursor, recs, E);
        sort2_kernel<<<NB, 256, 0, stream>>>(recs, off, srcs, noff, dinv, N, E);
        linear_kernel<<<(N + 15) / 16, 256, 0, stream>>>(x, dinv, W1, hA, N);
        agg_csr_kernel<<<(N + 15) / 16, 256, 0, stream>>>(hA, srcs, noff, dinv, W2, b1, hB, N, 1);
        agg_csr_kernel<<<(N + 15) / 16, 256, 0, stream>>>(hB, srcs, noff, dinv, nullptr, b2, outp, N, 2);
    } else {
        // R1 fallback: atomic scatter path (13.2MB ws)
        float* dinv = (float*)d_ws;
        float* h = dinv + N;
        float* acc = h + (size_t)F * N;
        hipMemsetAsync(dinv, 0, (size_t)N * sizeof(float), stream);
        hipMemsetAsync(acc, 0, (size_t)F * N * sizeof(float), stream);
        deg_kernel<<<(E + 255) / 256, 256, 0, stream>>>(dst, dinv, E);
        dinv_kernel<<<(N + 255) / 256, 256, 0, stream>>>(dinv, N);
        linear2_kernel<<<(N + 15) / 16, 256, 0, stream>>>(x, nullptr, dinv, W1, nullptr, h, N, 0);
        scatter_kernel<<<((size_t)E * F + 255) / 256, 256, 0, stream>>>(src, dst, h, acc, E);
        linear2_kernel<<<(N + 15) / 16, 256, 0, stream>>>(h, acc, dinv, W2, b1, h, N, 1);
        hipMemsetAsync(acc, 0, (size_t)F * N * sizeof(float), stream);
        scatter_kernel<<<((size_t)E * F + 255) / 256, 256, 0, stream>>>(src, dst, h, acc, E);
        out_kernel<<<((size_t)N * F + 255) / 256, 256, 0, stream>>>(acc, h, dinv, b2, outp, N);
    }
}

// Round 4
// 272.137 us; speedup vs baseline: 3.5981x; 1.6503x over previous
//
#include <hip/hip_runtime.h>

#define F 16
#define BSHIFT 8
#define NPB 256           // nodes per bucket = 1<<BSHIFT
#define NB 391            // buckets for N=100000: ceil(100000/256)
#define CH 4096           // edges per reorder block

// ========================= fast path kernels ================================

// block-privatized histogram of dst>>8 into bcount[NB]
__global__ void hist_kernel(const int* __restrict__ dst, unsigned* __restrict__ bcount, int E) {
    __shared__ unsigned lc[NB];
    for (int i = threadIdx.x; i < NB; i += blockDim.x) lc[i] = 0;
    __syncthreads();
    int stride = gridDim.x * blockDim.x;
    for (int e = blockIdx.x * blockDim.x + threadIdx.x; e < E; e += stride)
        atomicAdd(&lc[((unsigned)dst[e]) >> BSHIFT], 1u);
    __syncthreads();
    for (int i = threadIdx.x; i < NB; i += blockDim.x) {
        unsigned c = lc[i];
        if (c) atomicAdd(&bcount[i], c);
    }
}

// single-block exclusive scan of NB counts -> off[], cursor[] (cursor padded x16)
__global__ void scan_kernel(const unsigned* __restrict__ bcount, int* __restrict__ off,
                            unsigned* __restrict__ cursor, int E) {
    __shared__ unsigned s[2048];
    int t = threadIdx.x; // 1024 threads
    unsigned c0 = (t < NB) ? bcount[t] : 0u;
    unsigned c1 = (t + 1024 < NB) ? bcount[t + 1024] : 0u;
    s[t] = c0; s[t + 1024] = c1;
    __syncthreads();
    for (int d = 1; d < 2048; d <<= 1) {
        unsigned a  = (t >= d) ? s[t - d] : 0u;
        unsigned bv = (t + 1024 >= d) ? s[t + 1024 - d] : 0u;
        __syncthreads();
        s[t] += a; s[t + 1024] += bv;
        __syncthreads();
    }
    if (t < NB)       { unsigned ex = s[t] - c0;       off[t] = ex;       cursor[t * 16] = ex; }
    if (t + 1024 < NB){ unsigned ex = s[t+1024] - c1;  off[t+1024] = ex;  cursor[(t+1024)*16] = ex; }
    if (t == 0) off[NB] = E;
}

// bucket reorder with block-privatized range reservation.
// Each block: cache 4096 edges in LDS, LDS histogram, ONE global fetch-add per
// touched bucket to reserve a contiguous run, then write runs from LDS.
// rec = src | (dst&255)<<17
__global__ void reorder_kernel(const int* __restrict__ src, const int* __restrict__ dst,
                               unsigned* __restrict__ cursor, unsigned* __restrict__ recs, int E) {
    __shared__ unsigned lh[NB];
    __shared__ unsigned lsrc[CH];
    __shared__ unsigned ldst[CH];
    int t = threadIdx.x, b = blockIdx.x;
    int e0 = b * CH;
    int cnt_e = E - e0; if (cnt_e > CH) cnt_e = CH;
    for (int i = t; i < NB; i += 256) lh[i] = 0;
    __syncthreads();
    for (int i = t; i < cnt_e; i += 256) {
        unsigned d = (unsigned)dst[e0 + i];
        lsrc[i] = (unsigned)src[e0 + i];
        ldst[i] = d;
        atomicAdd(&lh[d >> BSHIFT], 1u);
    }
    __syncthreads();
    for (int i = t; i < NB; i += 256) {
        unsigned c = lh[i];
        lh[i] = c ? atomicAdd(&cursor[i * 16], c) : 0u;
    }
    __syncthreads();
    for (int i = t; i < cnt_e; i += 256) {
        unsigned d = ldst[i];
        unsigned pos = atomicAdd(&lh[d >> BSHIFT], 1u);
        recs[pos] = lsrc[i] | ((d & (NPB - 1u)) << 17);
    }
}

// per-bucket node-granularity sort: recs (bucket-sorted) -> srcs (dst-sorted),
// plus CSR offsets noff[] and dinv[] from the LDS degree histogram.
__global__ void sort2_kernel(const unsigned* __restrict__ recs, const int* __restrict__ off,
                             unsigned* __restrict__ srcs, int* __restrict__ noff,
                             float* __restrict__ dinv, int n, int E) {
    __shared__ unsigned cnt[NPB];
    __shared__ unsigned curs[NPB];
    __shared__ unsigned wtot[4];
    int t = threadIdx.x, b = blockIdx.x;   // 256 threads == NPB
    cnt[t] = 0;
    __syncthreads();
    int e0 = off[b], e1 = off[b + 1];
    for (int e = e0 + t; e < e1; e += 256) atomicAdd(&cnt[recs[e] >> 17], 1u);
    __syncthreads();
    unsigned c = cnt[t];
    unsigned inc = c;
    int lane = t & 63, w = t >> 6;
#pragma unroll
    for (int d = 1; d < 64; d <<= 1) {
        unsigned o = __shfl_up(inc, d, 64);
        if (lane >= d) inc += o;
    }
    if (lane == 63) wtot[w] = inc;
    __syncthreads();
    unsigned wbase = 0;
    for (int i = 0; i < w; ++i) wbase += wtot[i];
    unsigned ex = wbase + inc - c;
    curs[t] = (unsigned)e0 + ex;
    int node = b * NPB + t;
    if (node < n) {
        noff[node] = e0 + (int)ex;
        dinv[node] = rsqrtf((float)c + 1.0f);
    }
    if (b == (int)gridDim.x - 1 && t == 0) noff[n] = E;
    __syncthreads();
    for (int e = e0 + t; e < e1; e += 256) {
        unsigned rec = recs[e];
        unsigned pos = atomicAdd(&curs[rec >> 17], 1u);
        srcs[pos] = rec & 0x1FFFFu;
    }
}

// h[i,:] = (x[i,:] @ W) * dinv[i]    (16 nodes/block, 16 feats/node)
__global__ void linear_kernel(const float* __restrict__ in, const float* __restrict__ dinv,
                              const float* __restrict__ W, float* __restrict__ out, int n) {
    __shared__ float Ws[F * F];
    __shared__ float As[16][F + 1];
    int t = threadIdx.x;
    Ws[t] = W[t];
    int nb = t >> 4, j = t & 15;
    int i = blockIdx.x * 16 + nb;
    float di = 0.f, v = 0.f;
    if (i < n) { di = dinv[i]; v = in[i * F + j]; }
    As[nb][j] = v;
    __syncthreads();
    if (i < n) {
        float s = 0.f;
#pragma unroll
        for (int k = 0; k < F; ++k) s += As[nb][k] * Ws[k * F + j];
        out[i * F + j] = s * di;
    }
}

// atomic-free CSR aggregation, one 16-lane group per node, fused epilogue.
// s = sum over in-edges of hin[src,:]; v = dinv*(s + hin[node,:]) + bias
// mode 1: out = (relu(v) @ Wn) * dinv      (mid layer)
// mode 2: out = v                          (final layer)
__global__ void agg_csr_kernel(const float* __restrict__ hin, const unsigned* __restrict__ srcs,
                               const int* __restrict__ noff, const float* __restrict__ dinv,
                               const float* __restrict__ Wn, const float* __restrict__ bias,
                               float* __restrict__ outp, int n, int mode) {
    __shared__ float a1[16][F + 1];
    __shared__ float Ws[F * F];
    int t = threadIdx.x;
    int g = t >> 4, j = t & 15;
    if (mode == 1) Ws[t] = Wn[t];
    int node = blockIdx.x * 16 + g;
    float val = 0.f, di = 0.f;
    if (node < n) {
        di = dinv[node];
        int e0 = noff[node], e1 = noff[node + 1];
        float s0 = 0.f, s1 = 0.f, s2 = 0.f, s3 = 0.f;
        int e = e0;
        for (; e + 4 <= e1; e += 4) {
            int sa = srcs[e], sb = srcs[e + 1], sc = srcs[e + 2], sd = srcs[e + 3];
            s0 += hin[sa * F + j];
            s1 += hin[sb * F + j];
            s2 += hin[sc * F + j];
            s3 += hin[sd * F + j];
        }
        for (; e < e1; ++e) s0 += hin[srcs[e] * F + j];
        float s = (s0 + s1) + (s2 + s3);
        val = di * (s + hin[node * F + j]) + bias[j];
        if (mode == 1) val = fmaxf(val, 0.f);
    }
    if (mode == 1) {
        a1[g][j] = val;
        __syncthreads();
        if (node < n) {
            float s2 = 0.f;
#pragma unroll
            for (int k = 0; k < F; ++k) s2 += a1[g][k] * Ws[k * F + j];
            outp[node * F + j] = s2 * di;
        }
    } else {
        if (node < n) outp[node * F + j] = val;
    }
}

// ========================= fallback (R1) kernels ============================

__global__ void deg_kernel(const int* __restrict__ dst, float* __restrict__ deg, int E) {
    int e = blockIdx.x * blockDim.x + threadIdx.x;
    if (e < E) atomicAdd(&deg[dst[e]], 1.0f);
}
__global__ void dinv_kernel(float* __restrict__ deg, int n) {
    int i = blockIdx.x * blockDim.x + threadIdx.x;
    if (i < n) deg[i] = rsqrtf(deg[i] + 1.0f);
}
__global__ void linear2_kernel(const float* __restrict__ in, const float* __restrict__ acc,
                               const float* __restrict__ dinv, const float* __restrict__ W,
                               const float* __restrict__ bias, float* __restrict__ out,
                               int n, int mode) {
    __shared__ float Ws[F * F];
    __shared__ float As[16][F + 1];
    int t = threadIdx.x;
    Ws[t] = W[t];
    int nb = t >> 4, j = t & 15;
    int i = blockIdx.x * 16 + nb;
    float di = 0.f, v = 0.f;
    if (i < n) {
        di = dinv[i]; v = in[i * F + j];
        if (mode) { v = di * (acc[i * F + j] + v) + bias[j]; v = fmaxf(v, 0.f); }
    }
    As[nb][j] = v;
    __syncthreads();
    if (i < n) {
        float s = 0.f;
#pragma unroll
        for (int k = 0; k < F; ++k) s += As[nb][k] * Ws[k * F + j];
        out[i * F + j] = s * di;
    }
}
__global__ void scatter_kernel(const int* __restrict__ src, const int* __restrict__ dst,
                               const float* __restrict__ h, float* __restrict__ acc, int E) {
    int t = blockIdx.x * blockDim.x + threadIdx.x;
    int e = t >> 4, j = t & 15;
    if (e < E) atomicAdd(&acc[dst[e] * F + j], h[src[e] * F + j]);
}
__global__ void out_kernel(const float* __restrict__ acc, const float* __restrict__ h,
                           const float* __restrict__ dinv, const float* __restrict__ bias,
                           float* __restrict__ out, int n) {
    int t = blockIdx.x * blockDim.x + threadIdx.x;
    if (t < n * F) {
        int i = t >> 4, j = t & 15;
        out[t] = dinv[i] * (acc[t] + h[t]) + bias[j];
    }
}

// ========================= launch ===========================================

extern "C" void kernel_launch(void* const* d_in, const int* in_sizes, int n_in,
                              void* d_out, int out_size, void* d_ws, size_t ws_size,
                              hipStream_t stream) {
    const float* x  = (const float*)d_in[0];
    const int*   ei = (const int*)d_in[1];
    const float* W1 = (const float*)d_in[2];
    const float* b1 = (const float*)d_in[3];
    const float* W2 = (const float*)d_in[4];
    const float* b2 = (const float*)d_in[5];
    float* outp = (float*)d_out;

    const int N = in_sizes[0] / F;
    const int E = in_sizes[1] / 2;
    const int* src = ei;
    const int* dst = ei + E;

    const int nb_rt = (N + NPB - 1) >> BSHIFT;
    // ws layout (4B units): dinv[N] | hA[16N] | hB[16N] | recs[E] | srcs[E] |
    //                       noff[N+1] | bcount[NB] | off[NB+1] | cursor[16*NB]
    size_t need = sizeof(float) * ((size_t)N * 33 + (N + 1)
                                   + 2 * (size_t)E + NB + (NB + 1) + 16 * NB);

    if (nb_rt == NB && ws_size >= need) {
        float* dinv = (float*)d_ws;
        float* hA = dinv + N;
        float* hB = hA + (size_t)F * N;
        unsigned* recs = (unsigned*)(hB + (size_t)F * N);
        unsigned* srcs = recs + E;
        int* noff = (int*)(srcs + E);
        unsigned* bcount = (unsigned*)(noff + N + 1);
        int* off = (int*)(bcount + NB);
        unsigned* cursor = (unsigned*)(off + NB + 1);

        hipMemsetAsync(bcount, 0, NB * sizeof(unsigned), stream);
        hist_kernel<<<256, 256, 0, stream>>>(dst, bcount, E);
        scan_kernel<<<1, 1024, 0, stream>>>(bcount, off, cursor, E);
        reorder_kernel<<<(E + CH - 1) / CH, 256, 0, stream>>>(src, dst, cursor, recs, E);
        sort2_kernel<<<NB, 256, 0, stream>>>(recs, off, srcs, noff, dinv, N, E);
        linear_kernel<<<(N + 15) / 16, 256, 0, stream>>>(x, dinv, W1, hA, N);
        agg_csr_kernel<<<(N + 15) / 16, 256, 0, stream>>>(hA, srcs, noff, dinv, W2, b1, hB, N, 1);
        agg_csr_kernel<<<(N + 15) / 16, 256, 0, stream>>>(hB, srcs, noff, dinv, nullptr, b2, outp, N, 2);
    } else {
        // R1 fallback: atomic scatter path (13.2MB ws)
        float* dinv = (float*)d_ws;
        float* h = dinv + N;
        float* acc = h + (size_t)F * N;
        hipMemsetAsync(dinv, 0, (size_t)N * sizeof(float), stream);
        hipMemsetAsync(acc, 0, (size_t)F * N * sizeof(float), stream);
        deg_kernel<<<(E + 255) / 256, 256, 0, stream>>>(dst, dinv, E);
        dinv_kernel<<<(N + 255) / 256, 256, 0, stream>>>(dinv, N);
        linear2_kernel<<<(N + 15) / 16, 256, 0, stream>>>(x, nullptr, dinv, W1, nullptr, h, N, 0);
        scatter_kernel<<<((size_t)E * F + 255) / 256, 256, 0, stream>>>(src, dst, h, acc, E);
        linear2_kernel<<<(N + 15) / 16, 256, 0, stream>>>(h, acc, dinv, W2, b1, h, N, 1);
        hipMemsetAsync(acc, 0, (size_t)F * N * sizeof(float), stream);
        scatter_kernel<<<((size_t)E * F + 255) / 256, 256, 0, stream>>>(src, dst, h, acc, E);
        out_kernel<<<((size_t)N * F + 255) / 256, 256, 0, stream>>>(acc, h, dinv, b2, outp, N);
    }
}

// Round 5
// 259.254 us; speedup vs baseline: 3.7769x; 1.0497x over previous
//
#include <hip/hip_runtime.h>

#define F 16
#define BSHIFT 8
#define NPB 256           // nodes per bucket = 1<<BSHIFT
#define NB 391            // buckets for N=100000: ceil(100000/256)
#define CH 4096           // edges per reorder block

// ========================= fast path kernels ================================

// block-privatized histogram of dst>>8 into bcount[NB], int4-vectorized
__global__ void hist_kernel(const int* __restrict__ dst, unsigned* __restrict__ bcount, int E) {
    __shared__ unsigned lc[NB];
    for (int i = threadIdx.x; i < NB; i += blockDim.x) lc[i] = 0;
    __syncthreads();
    int E4 = E >> 2;
    const int4* d4 = (const int4*)dst;
    int stride = gridDim.x * blockDim.x;
    for (int e = blockIdx.x * blockDim.x + threadIdx.x; e < E4; e += stride) {
        int4 v = d4[e];
        atomicAdd(&lc[((unsigned)v.x) >> BSHIFT], 1u);
        atomicAdd(&lc[((unsigned)v.y) >> BSHIFT], 1u);
        atomicAdd(&lc[((unsigned)v.z) >> BSHIFT], 1u);
        atomicAdd(&lc[((unsigned)v.w) >> BSHIFT], 1u);
    }
    // tail
    for (int e = E4 * 4 + blockIdx.x * blockDim.x + threadIdx.x; e < E; e += stride)
        atomicAdd(&lc[((unsigned)dst[e]) >> BSHIFT], 1u);
    __syncthreads();
    for (int i = threadIdx.x; i < NB; i += blockDim.x) {
        unsigned c = lc[i];
        if (c) atomicAdd(&bcount[i], c);
    }
}

// single-block exclusive scan of NB counts -> off[], cursor[] (cursor padded x16)
__global__ void scan_kernel(const unsigned* __restrict__ bcount, int* __restrict__ off,
                            unsigned* __restrict__ cursor, int E) {
    __shared__ unsigned s[2048];
    int t = threadIdx.x; // 1024 threads
    unsigned c0 = (t < NB) ? bcount[t] : 0u;
    unsigned c1 = (t + 1024 < NB) ? bcount[t + 1024] : 0u;
    s[t] = c0; s[t + 1024] = c1;
    __syncthreads();
    for (int d = 1; d < 2048; d <<= 1) {
        unsigned a  = (t >= d) ? s[t - d] : 0u;
        unsigned bv = (t + 1024 >= d) ? s[t + 1024 - d] : 0u;
        __syncthreads();
        s[t] += a; s[t + 1024] += bv;
        __syncthreads();
    }
    if (t < NB)       { unsigned ex = s[t] - c0;       off[t] = ex;       cursor[t * 16] = ex; }
    if (t + 1024 < NB){ unsigned ex = s[t+1024] - c1;  off[t+1024] = ex;  cursor[(t+1024)*16] = ex; }
    if (t == 0) off[NB] = E;
}

// bucket reorder, LDS counting-sort per 4096-edge chunk, contiguous run writes.
// rec = src | (dst&255)<<17
__global__ void reorder_kernel(const int* __restrict__ src, const int* __restrict__ dst,
                               unsigned* __restrict__ cursor, unsigned* __restrict__ recs, int E) {
    __shared__ unsigned lsorted[CH];
    __shared__ unsigned short lbkt[CH];
    __shared__ unsigned lstart[NB + 1];
    __shared__ unsigned lcur[NB];
    __shared__ int ldelta[NB];
    int t = threadIdx.x, b = blockIdx.x;
    int e0 = b * CH;
    int cnt_e = E - e0; if (cnt_e > CH) cnt_e = CH;

    for (int i = t; i < NB; i += 256) lcur[i] = 0;   // reuse lcur as counts
    __syncthreads();
    // phase 1: histogram (read dst coalesced)
    for (int i = t; i < cnt_e; i += 256)
        atomicAdd(&lcur[((unsigned)dst[e0 + i]) >> BSHIFT], 1u);
    __syncthreads();
    // phase 2: exclusive scan of 391 counts by wave 0 (7 chunks of 64)
    if (t < 64) {
        unsigned run = 0;
        for (int c = 0; c < NB; c += 64) {
            int idx = c + t;
            unsigned v = (idx < NB) ? lcur[idx] : 0u;
            unsigned inc = v;
#pragma unroll
            for (int d = 1; d < 64; d <<= 1) {
                unsigned o = __shfl_up(inc, d, 64);
                if (t >= d) inc += o;
            }
            if (idx <= NB) lstart[idx] = run + inc - v;
            unsigned tot = __shfl(inc, 63, 64);
            if (t == 63 && idx < NB) lstart[idx + 1] = run + inc;  // running edge
            run += tot;
        }
        if (t == 0) lstart[NB] = (unsigned)cnt_e;
    }
    __syncthreads();
    // phase 3: reserve global ranges, init cursors
    for (int i = t; i < NB; i += 256) {
        unsigned st = lstart[i];
        unsigned cnt = lstart[i + 1] - st;
        lcur[i] = st;
        if (cnt) {
            unsigned g = atomicAdd(&cursor[i * 16], cnt);
            ldelta[i] = (int)g - (int)st;
        }
    }
    __syncthreads();
    // phase 4: LDS scatter into sorted order (re-read src/dst, L2-hot)
    for (int i = t; i < cnt_e; i += 256) {
        unsigned d = (unsigned)dst[e0 + i];
        unsigned s = (unsigned)src[e0 + i];
        unsigned bk = d >> BSHIFT;
        unsigned pos = atomicAdd(&lcur[bk], 1u);
        lsorted[pos] = s | ((d & (NPB - 1u)) << 17);
        lbkt[pos] = (unsigned short)bk;
    }
    __syncthreads();
    // phase 5: contiguous write-out: sorted slot i -> recs[delta[bkt]+i]
    for (int i = t; i < cnt_e; i += 256) {
        unsigned bk = lbkt[i];
        recs[ldelta[bk] + i] = lsorted[i];
    }
}

// per-bucket node-granularity sort: recs (bucket-sorted) -> srcs (dst-sorted),
// plus CSR offsets noff[] and dinv[] from the LDS degree histogram. 1024 thr.
__global__ void sort2_kernel(const unsigned* __restrict__ recs, const int* __restrict__ off,
                             unsigned* __restrict__ srcs, int* __restrict__ noff,
                             float* __restrict__ dinv, int n, int E) {
    __shared__ unsigned cnt[NPB];
    __shared__ unsigned curs[NPB];
    __shared__ unsigned wtot[4];
    int t = threadIdx.x, b = blockIdx.x;   // 1024 threads
    if (t < NPB) cnt[t] = 0;
    __syncthreads();
    int e0 = off[b], e1 = off[b + 1];
    for (int e = e0 + t; e < e1; e += 1024) atomicAdd(&cnt[recs[e] >> 17], 1u);
    __syncthreads();
    if (t < NPB) {
        unsigned c = cnt[t];
        unsigned inc = c;
        int lane = t & 63, w = t >> 6;
#pragma unroll
        for (int d = 1; d < 64; d <<= 1) {
            unsigned o = __shfl_up(inc, d, 64);
            if (lane >= d) inc += o;
        }
        if (lane == 63) wtot[w] = inc;
        __syncthreads();
        unsigned wbase = 0;
        for (int i = 0; i < w; ++i) wbase += wtot[i];
        unsigned ex = wbase + inc - c;
        curs[t] = (unsigned)e0 + ex;
        int node = b * NPB + t;
        if (node < n) {
            noff[node] = e0 + (int)ex;
            dinv[node] = rsqrtf((float)c + 1.0f);
        }
    } else {
        __syncthreads();
    }
    if (b == (int)gridDim.x - 1 && t == 0) noff[n] = E;
    __syncthreads();
    for (int e = e0 + t; e < e1; e += 1024) {
        unsigned rec = recs[e];
        unsigned pos = atomicAdd(&curs[rec >> 17], 1u);
        srcs[pos] = rec & 0x1FFFFu;
    }
}

// h[i,:] = (x[i,:] @ W) * dinv[i]    (16 nodes/block, 16 feats/node)
__global__ void linear_kernel(const float* __restrict__ in, const float* __restrict__ dinv,
                              const float* __restrict__ W, float* __restrict__ out, int n) {
    __shared__ float Ws[F * F];
    __shared__ float As[16][F + 1];
    int t = threadIdx.x;
    Ws[t] = W[t];
    int nb = t >> 4, j = t & 15;
    int i = blockIdx.x * 16 + nb;
    float di = 0.f, v = 0.f;
    if (i < n) { di = dinv[i]; v = in[i * F + j]; }
    As[nb][j] = v;
    __syncthreads();
    if (i < n) {
        float s = 0.f;
#pragma unroll
        for (int k = 0; k < F; ++k) s += As[nb][k] * Ws[k * F + j];
        out[i * F + j] = s * di;
    }
}

// atomic-free CSR aggregation, one 16-lane group per node, fused epilogue.
// s = sum over in-edges of hin[src,:]; v = dinv*(s + hin[node,:]) + bias
// mode 1: out = (relu(v) @ Wn) * dinv      (mid layer)
// mode 2: out = v                          (final layer)
__global__ void agg_csr_kernel(const float* __restrict__ hin, const unsigned* __restrict__ srcs,
                               const int* __restrict__ noff, const float* __restrict__ dinv,
                               const float* __restrict__ Wn, const float* __restrict__ bias,
                               float* __restrict__ outp, int n, int mode) {
    __shared__ float a1[16][F + 1];
    __shared__ float Ws[F * F];
    int t = threadIdx.x;
    int g = t >> 4, j = t & 15;
    if (mode == 1) Ws[t] = Wn[t];
    int node = blockIdx.x * 16 + g;
    float val = 0.f, di = 0.f;
    if (node < n) {
        di = dinv[node];
        int e0 = noff[node], e1 = noff[node + 1];
        float s0 = 0.f, s1 = 0.f, s2 = 0.f, s3 = 0.f;
        int e = e0;
        for (; e + 4 <= e1; e += 4) {
            int sa = srcs[e], sb = srcs[e + 1], sc = srcs[e + 2], sd = srcs[e + 3];
            s0 += hin[sa * F + j];
            s1 += hin[sb * F + j];
            s2 += hin[sc * F + j];
            s3 += hin[sd * F + j];
        }
        for (; e < e1; ++e) s0 += hin[srcs[e] * F + j];
        float s = (s0 + s1) + (s2 + s3);
        val = di * (s + hin[node * F + j]) + bias[j];
        if (mode == 1) val = fmaxf(val, 0.f);
    }
    if (mode == 1) {
        a1[g][j] = val;
        __syncthreads();
        if (node < n) {
            float s2 = 0.f;
#pragma unroll
            for (int k = 0; k < F; ++k) s2 += a1[g][k] * Ws[k * F + j];
            outp[node * F + j] = s2 * di;
        }
    } else {
        if (node < n) outp[node * F + j] = val;
    }
}

// ========================= fallback (R1) kernels ============================

__global__ void deg_kernel(const int* __restrict__ dst, float* __restrict__ deg, int E) {
    int e = blockIdx.x * blockDim.x + threadIdx.x;
    if (e < E) atomicAdd(&deg[dst[e]], 1.0f);
}
__global__ void dinv_kernel(float* __restrict__ deg, int n) {
    int i = blockIdx.x * blockDim.x + threadIdx.x;
    if (i < n) deg[i] = rsqrtf(deg[i] + 1.0f);
}
__global__ void linear2_kernel(const float* __restrict__ in, const float* __restrict__ acc,
                               const float* __restrict__ dinv, const float* __restrict__ W,
                               const float* __restrict__ bias, float* __restrict__ out,
                               int n, int mode) {
    __shared__ float Ws[F * F];
    __shared__ float As[16][F + 1];
    int t = threadIdx.x;
    Ws[t] = W[t];
    int nb = t >> 4, j = t & 15;
    int i = blockIdx.x * 16 + nb;
    float di = 0.f, v = 0.f;
    if (i < n) {
        di = dinv[i]; v = in[i * F + j];
        if (mode) { v = di * (acc[i * F + j] + v) + bias[j]; v = fmaxf(v, 0.f); }
    }
    As[nb][j] = v;
    __syncthreads();
    if (i < n) {
        float s = 0.f;
#pragma unroll
        for (int k = 0; k < F; ++k) s += As[nb][k] * Ws[k * F + j];
        out[i * F + j] = s * di;
    }
}
__global__ void scatter_kernel(const int* __restrict__ src, const int* __restrict__ dst,
                               const float* __restrict__ h, float* __restrict__ acc, int E) {
    int t = blockIdx.x * blockDim.x + threadIdx.x;
    int e = t >> 4, j = t & 15;
    if (e < E) atomicAdd(&acc[dst[e] * F + j], h[src[e] * F + j]);
}
__global__ void out_kernel(const float* __restrict__ acc, const float* __restrict__ h,
                           const float* __restrict__ dinv, const float* __restrict__ bias,
                           float* __restrict__ out, int n) {
    int t = blockIdx.x * blockDim.x + threadIdx.x;
    if (t < n * F) {
        int i = t >> 4, j = t & 15;
        out[t] = dinv[i] * (acc[t] + h[t]) + bias[j];
    }
}

// ========================= launch ===========================================

extern "C" void kernel_launch(void* const* d_in, const int* in_sizes, int n_in,
                              void* d_out, int out_size, void* d_ws, size_t ws_size,
                              hipStream_t stream) {
    const float* x  = (const float*)d_in[0];
    const int*   ei = (const int*)d_in[1];
    const float* W1 = (const float*)d_in[2];
    const float* b1 = (const float*)d_in[3];
    const float* W2 = (const float*)d_in[4];
    const float* b2 = (const float*)d_in[5];
    float* outp = (float*)d_out;

    const int N = in_sizes[0] / F;
    const int E = in_sizes[1] / 2;
    const int* src = ei;
    const int* dst = ei + E;

    const int nb_rt = (N + NPB - 1) >> BSHIFT;
    // ws layout (4B units): dinv[N] | hA[16N] | hB[16N] | recs[E] | srcs[E] |
    //                       noff[N+1] | bcount[NB] | off[NB+1] | cursor[16*NB]
    size_t need = sizeof(float) * ((size_t)N * 33 + (N + 1)
                                   + 2 * (size_t)E + NB + (NB + 1) + 16 * NB);

    if (nb_rt == NB && ws_size >= need) {
        float* dinv = (float*)d_ws;
        float* hA = dinv + N;
        float* hB = hA + (size_t)F * N;
        unsigned* recs = (unsigned*)(hB + (size_t)F * N);
        unsigned* srcs = recs + E;
        int* noff = (int*)(srcs + E);
        unsigned* bcount = (unsigned*)(noff + N + 1);
        int* off = (int*)(bcount + NB);
        unsigned* cursor = (unsigned*)(off + NB + 1);

        hipMemsetAsync(bcount, 0, NB * sizeof(unsigned), stream);
        hist_kernel<<<512, 256, 0, stream>>>(dst, bcount, E);
        scan_kernel<<<1, 1024, 0, stream>>>(bcount, off, cursor, E);
        reorder_kernel<<<(E + CH - 1) / CH, 256, 0, stream>>>(src, dst, cursor, recs, E);
        sort2_kernel<<<NB, 1024, 0, stream>>>(recs, off, srcs, noff, dinv, N, E);
        linear_kernel<<<(N + 15) / 16, 256, 0, stream>>>(x, dinv, W1, hA, N);
        agg_csr_kernel<<<(N + 15) / 16, 256, 0, stream>>>(hA, srcs, noff, dinv, W2, b1, hB, N, 1);
        agg_csr_kernel<<<(N + 15) / 16, 256, 0, stream>>>(hB, srcs, noff, dinv, nullptr, b2, outp, N, 2);
    } else {
        // R1 fallback: atomic scatter path (13.2MB ws)
        float* dinv = (float*)d_ws;
        float* h = dinv + N;
        float* acc = h + (size_t)F * N;
        hipMemsetAsync(dinv, 0, (size_t)N * sizeof(float), stream);
        hipMemsetAsync(acc, 0, (size_t)F * N * sizeof(float), stream);
        deg_kernel<<<(E + 255) / 256, 256, 0, stream>>>(dst, dinv, E);
        dinv_kernel<<<(N + 255) / 256, 256, 0, stream>>>(dinv, N);
        linear2_kernel<<<(N + 15) / 16, 256, 0, stream>>>(x, nullptr, dinv, W1, nullptr, h, N, 0);
        scatter_kernel<<<((size_t)E * F + 255) / 256, 256, 0, stream>>>(src, dst, h, acc, E);
        linear2_kernel<<<(N + 15) / 16, 256, 0, stream>>>(h, acc, dinv, W2, b1, h, N, 1);
        hipMemsetAsync(acc, 0, (size_t)F * N * sizeof(float), stream);
        scatter_kernel<<<((size_t)E * F + 255) / 256, 256, 0, stream>>>(src, dst, h, acc, E);
        out_kernel<<<((size_t)N * F + 255) / 256, 256, 0, stream>>>(acc, h, dinv, b2, outp, N);
    }
}

// Round 6
// 242.639 us; speedup vs baseline: 4.0355x; 1.0685x over previous
//
#include <hip/hip_runtime.h>

#define F 16
#define BSHIFT 8
#define NPB 256           // nodes per bucket = 1<<BSHIFT
#define NB 391            // buckets for N=100000: ceil(100000/256)
#define CH 4096           // edges per reorder block

// ========================= fast path kernels ================================

// block-privatized histogram of dst>>8 into bcount[NB], int4-vectorized
__global__ void hist_kernel(const int* __restrict__ dst, unsigned* __restrict__ bcount, int E) {
    __shared__ unsigned lc[NB];
    for (int i = threadIdx.x; i < NB; i += blockDim.x) lc[i] = 0;
    __syncthreads();
    int E4 = E >> 2;
    const int4* d4 = (const int4*)dst;
    int stride = gridDim.x * blockDim.x;
    for (int e = blockIdx.x * blockDim.x + threadIdx.x; e < E4; e += stride) {
        int4 v = d4[e];
        atomicAdd(&lc[((unsigned)v.x) >> BSHIFT], 1u);
        atomicAdd(&lc[((unsigned)v.y) >> BSHIFT], 1u);
        atomicAdd(&lc[((unsigned)v.z) >> BSHIFT], 1u);
        atomicAdd(&lc[((unsigned)v.w) >> BSHIFT], 1u);
    }
    for (int e = E4 * 4 + blockIdx.x * blockDim.x + threadIdx.x; e < E; e += stride)
        atomicAdd(&lc[((unsigned)dst[e]) >> BSHIFT], 1u);
    __syncthreads();
    for (int i = threadIdx.x; i < NB; i += blockDim.x) {
        unsigned c = lc[i];
        if (c) atomicAdd(&bcount[i], c);
    }
}

// single-block exclusive scan of NB counts -> off[], cursor[] (cursor padded x16)
__global__ void scan_kernel(const unsigned* __restrict__ bcount, int* __restrict__ off,
                            unsigned* __restrict__ cursor, int E) {
    __shared__ unsigned s[2048];
    int t = threadIdx.x; // 1024 threads
    unsigned c0 = (t < NB) ? bcount[t] : 0u;
    unsigned c1 = (t + 1024 < NB) ? bcount[t + 1024] : 0u;
    s[t] = c0; s[t + 1024] = c1;
    __syncthreads();
    for (int d = 1; d < 2048; d <<= 1) {
        unsigned a  = (t >= d) ? s[t - d] : 0u;
        unsigned bv = (t + 1024 >= d) ? s[t + 1024 - d] : 0u;
        __syncthreads();
        s[t] += a; s[t + 1024] += bv;
        __syncthreads();
    }
    if (t < NB)       { unsigned ex = s[t] - c0;       off[t] = ex;       cursor[t * 16] = ex; }
    if (t + 1024 < NB){ unsigned ex = s[t+1024] - c1;  off[t+1024] = ex;  cursor[(t+1024)*16] = ex; }
    if (t == 0) off[NB] = E;
}

// bucket reorder, LDS counting-sort per 4096-edge chunk. 512 threads/block.
// rec = src | (dst&255)<<17
__global__ void reorder_kernel(const int* __restrict__ src, const int* __restrict__ dst,
                               unsigned* __restrict__ cursor, unsigned* __restrict__ recs, int E) {
    __shared__ unsigned lsorted[CH];
    __shared__ unsigned short lbkt[CH];
    __shared__ unsigned lstart[NB + 1];
    __shared__ unsigned lcur[NB];
    __shared__ int ldelta[NB];
    int t = threadIdx.x, b = blockIdx.x;
    int e0 = b * CH;
    int cnt_e = E - e0; if (cnt_e > CH) cnt_e = CH;
    int i4 = cnt_e >> 2;
    const int4* dst4 = (const int4*)(dst + e0);
    const int4* src4 = (const int4*)(src + e0);

    for (int i = t; i < NB; i += 512) lcur[i] = 0;   // reuse lcur as counts
    __syncthreads();
    // phase 1: histogram (int4 coalesced)
    for (int i = t; i < i4; i += 512) {
        int4 d = dst4[i];
        atomicAdd(&lcur[((unsigned)d.x) >> BSHIFT], 1u);
        atomicAdd(&lcur[((unsigned)d.y) >> BSHIFT], 1u);
        atomicAdd(&lcur[((unsigned)d.z) >> BSHIFT], 1u);
        atomicAdd(&lcur[((unsigned)d.w) >> BSHIFT], 1u);
    }
    for (int i = i4 * 4 + t; i < cnt_e; i += 512)
        atomicAdd(&lcur[((unsigned)dst[e0 + i]) >> BSHIFT], 1u);
    __syncthreads();
    // phase 2: exclusive scan of NB counts by wave 0
    if (t < 64) {
        unsigned run = 0;
        for (int c = 0; c < NB; c += 64) {
            int idx = c + t;
            unsigned v = (idx < NB) ? lcur[idx] : 0u;
            unsigned inc = v;
#pragma unroll
            for (int d = 1; d < 64; d <<= 1) {
                unsigned o = __shfl_up(inc, d, 64);
                if (t >= d) inc += o;
            }
            if (idx <= NB) lstart[idx] = run + inc - v;
            unsigned tot = __shfl(inc, 63, 64);
            if (t == 63 && idx < NB) lstart[idx + 1] = run + inc;
            run += tot;
        }
        if (t == 0) lstart[NB] = (unsigned)cnt_e;
    }
    __syncthreads();
    // phase 3: reserve global ranges, init cursors
    for (int i = t; i < NB; i += 512) {
        unsigned st = lstart[i];
        unsigned cnt = lstart[i + 1] - st;
        lcur[i] = st;
        if (cnt) {
            unsigned g = atomicAdd(&cursor[i * 16], cnt);
            ldelta[i] = (int)g - (int)st;
        }
    }
    __syncthreads();
    // phase 4: LDS scatter into sorted order (int4 reads)
    for (int i = t; i < i4; i += 512) {
        int4 d = dst4[i];
        int4 s = src4[i];
        unsigned dd, bk, pos;
        dd = (unsigned)d.x; bk = dd >> BSHIFT; pos = atomicAdd(&lcur[bk], 1u);
        lsorted[pos] = (unsigned)s.x | ((dd & (NPB - 1u)) << 17); lbkt[pos] = (unsigned short)bk;
        dd = (unsigned)d.y; bk = dd >> BSHIFT; pos = atomicAdd(&lcur[bk], 1u);
        lsorted[pos] = (unsigned)s.y | ((dd & (NPB - 1u)) << 17); lbkt[pos] = (unsigned short)bk;
        dd = (unsigned)d.z; bk = dd >> BSHIFT; pos = atomicAdd(&lcur[bk], 1u);
        lsorted[pos] = (unsigned)s.z | ((dd & (NPB - 1u)) << 17); lbkt[pos] = (unsigned short)bk;
        dd = (unsigned)d.w; bk = dd >> BSHIFT; pos = atomicAdd(&lcur[bk], 1u);
        lsorted[pos] = (unsigned)s.w | ((dd & (NPB - 1u)) << 17); lbkt[pos] = (unsigned short)bk;
    }
    for (int i = i4 * 4 + t; i < cnt_e; i += 512) {
        unsigned dd = (unsigned)dst[e0 + i];
        unsigned bk = dd >> BSHIFT;
        unsigned pos = atomicAdd(&lcur[bk], 1u);
        lsorted[pos] = (unsigned)src[e0 + i] | ((dd & (NPB - 1u)) << 17);
        lbkt[pos] = (unsigned short)bk;
    }
    __syncthreads();
    // phase 5: run-contiguous write-out: sorted slot i -> recs[delta[bkt]+i]
    for (int i = t; i < cnt_e; i += 512) {
        unsigned bk = lbkt[i];
        recs[ldelta[bk] + i] = lsorted[i];
    }
}

// per-bucket node-granularity sort: recs (bucket-sorted) -> srcs (dst-sorted),
// plus CSR offsets noff[] and dinv[] from the LDS degree histogram. 1024 thr.
__global__ void sort2_kernel(const unsigned* __restrict__ recs, const int* __restrict__ off,
                             unsigned* __restrict__ srcs, int* __restrict__ noff,
                             float* __restrict__ dinv, int n, int E) {
    __shared__ unsigned cnt[NPB];
    __shared__ unsigned curs[NPB];
    __shared__ unsigned wtot[4];
    int t = threadIdx.x, b = blockIdx.x;   // 1024 threads
    if (t < NPB) cnt[t] = 0;
    __syncthreads();
    int e0 = off[b], e1 = off[b + 1];
    for (int e = e0 + t; e < e1; e += 1024) atomicAdd(&cnt[recs[e] >> 17], 1u);
    __syncthreads();
    if (t < NPB) {
        unsigned c = cnt[t];
        unsigned inc = c;
        int lane = t & 63, w = t >> 6;
#pragma unroll
        for (int d = 1; d < 64; d <<= 1) {
            unsigned o = __shfl_up(inc, d, 64);
            if (lane >= d) inc += o;
        }
        if (lane == 63) wtot[w] = inc;
        __syncthreads();
        unsigned wbase = 0;
        for (int i = 0; i < w; ++i) wbase += wtot[i];
        unsigned ex = wbase + inc - c;
        curs[t] = (unsigned)e0 + ex;
        int node = b * NPB + t;
        if (node < n) {
            noff[node] = e0 + (int)ex;
            dinv[node] = rsqrtf((float)c + 1.0f);
        }
    } else {
        __syncthreads();
    }
    if (b == (int)gridDim.x - 1 && t == 0) noff[n] = E;
    __syncthreads();
    for (int e = e0 + t; e < e1; e += 1024) {
        unsigned rec = recs[e];
        unsigned pos = atomicAdd(&curs[rec >> 17], 1u);
        srcs[pos] = rec & 0x1FFFFu;
    }
}

// h[i,:] = (x[i,:] @ W) * dinv[i]  — 64 nodes/block, 4 lanes/node, float4
__global__ void linear_kernel(const float* __restrict__ in, const float* __restrict__ dinv,
                              const float* __restrict__ W, float* __restrict__ out, int n) {
    __shared__ float Ws[F * F];
    __shared__ float As[64][F + 1];
    int t = threadIdx.x;
    Ws[t] = W[t];
    int g = t >> 2, c = t & 3;
    int node = blockIdx.x * 64 + g;
    float4 v = {0.f, 0.f, 0.f, 0.f};
    if (node < n) v = ((const float4*)in)[(size_t)node * 4 + c];
    As[g][c * 4 + 0] = v.x; As[g][c * 4 + 1] = v.y;
    As[g][c * 4 + 2] = v.z; As[g][c * 4 + 3] = v.w;
    __syncthreads();
    if (node < n) {
        float di = dinv[node];
        float4 o = {0.f, 0.f, 0.f, 0.f};
        int j = c * 4;
#pragma unroll
        for (int k = 0; k < F; ++k) {
            float ak = As[g][k];
            o.x += ak * Ws[k * F + j + 0];
            o.y += ak * Ws[k * F + j + 1];
            o.z += ak * Ws[k * F + j + 2];
            o.w += ak * Ws[k * F + j + 3];
        }
        o.x *= di; o.y *= di; o.z *= di; o.w *= di;
        ((float4*)out)[(size_t)node * 4 + c] = o;
    }
}

// atomic-free CSR aggregation — 64 nodes/block, 4 lanes/node, float4 gathers.
// s = sum over in-edges of hin[src,:]; v = dinv*(s + hin[node,:]) + bias
// mode 1: out = (relu(v) @ Wn) * dinv      (mid layer)
// mode 2: out = v                          (final layer)
__global__ void agg_csr_kernel(const float* __restrict__ hin, const unsigned* __restrict__ srcs,
                               const int* __restrict__ noff, const float* __restrict__ dinv,
                               const float* __restrict__ Wn, const float* __restrict__ bias,
                               float* __restrict__ outp, int n, int mode) {
    __shared__ float a1[64][F + 1];
    __shared__ float Ws[F * F];
    int t = threadIdx.x;
    int g = t >> 2, c = t & 3;
    if (mode == 1) Ws[t] = Wn[t];
    int node = blockIdx.x * 64 + g;
    const float4* h4 = (const float4*)hin;
    float4 val = {0.f, 0.f, 0.f, 0.f};
    float di = 0.f;
    if (node < n) {
        di = dinv[node];
        int e0 = noff[node], e1 = noff[node + 1];
        float4 s0 = {0,0,0,0}, s1 = {0,0,0,0}, s2 = {0,0,0,0}, s3 = {0,0,0,0};
        int e = e0;
        for (; e + 4 <= e1; e += 4) {
            int ia = srcs[e], ib = srcs[e + 1], ic = srcs[e + 2], id = srcs[e + 3];
            float4 va = h4[(size_t)ia * 4 + c];
            float4 vb = h4[(size_t)ib * 4 + c];
            float4 vc = h4[(size_t)ic * 4 + c];
            float4 vd = h4[(size_t)id * 4 + c];
            s0.x += va.x; s0.y += va.y; s0.z += va.z; s0.w += va.w;
            s1.x += vb.x; s1.y += vb.y; s1.z += vb.z; s1.w += vb.w;
            s2.x += vc.x; s2.y += vc.y; s2.z += vc.z; s2.w += vc.w;
            s3.x += vd.x; s3.y += vd.y; s3.z += vd.z; s3.w += vd.w;
        }
        for (; e < e1; ++e) {
            float4 va = h4[(size_t)srcs[e] * 4 + c];
            s0.x += va.x; s0.y += va.y; s0.z += va.z; s0.w += va.w;
        }
        float4 self = h4[(size_t)node * 4 + c];
        float4 bi = ((const float4*)bias)[c];
        val.x = di * ((s0.x + s1.x) + (s2.x + s3.x) + self.x) + bi.x;
        val.y = di * ((s0.y + s1.y) + (s2.y + s3.y) + self.y) + bi.y;
        val.z = di * ((s0.z + s1.z) + (s2.z + s3.z) + self.z) + bi.z;
        val.w = di * ((s0.w + s1.w) + (s2.w + s3.w) + self.w) + bi.w;
        if (mode == 1) {
            val.x = fmaxf(val.x, 0.f); val.y = fmaxf(val.y, 0.f);
            val.z = fmaxf(val.z, 0.f); val.w = fmaxf(val.w, 0.f);
        }
    }
    if (mode == 1) {
        a1[g][c * 4 + 0] = val.x; a1[g][c * 4 + 1] = val.y;
        a1[g][c * 4 + 2] = val.z; a1[g][c * 4 + 3] = val.w;
        __syncthreads();
        if (node < n) {
            float4 o = {0.f, 0.f, 0.f, 0.f};
            int j = c * 4;
#pragma unroll
            for (int k = 0; k < F; ++k) {
                float ak = a1[g][k];
                o.x += ak * Ws[k * F + j + 0];
                o.y += ak * Ws[k * F + j + 1];
                o.z += ak * Ws[k * F + j + 2];
                o.w += ak * Ws[k * F + j + 3];
            }
            o.x *= di; o.y *= di; o.z *= di; o.w *= di;
            ((float4*)outp)[(size_t)node * 4 + c] = o;
        }
    } else {
        if (node < n) ((float4*)outp)[(size_t)node * 4 + c] = val;
    }
}

// ========================= fallback (R1) kernels ============================

__global__ void deg_kernel(const int* __restrict__ dst, float* __restrict__ deg, int E) {
    int e = blockIdx.x * blockDim.x + threadIdx.x;
    if (e < E) atomicAdd(&deg[dst[e]], 1.0f);
}
__global__ void dinv_kernel(float* __restrict__ deg, int n) {
    int i = blockIdx.x * blockDim.x + threadIdx.x;
    if (i < n) deg[i] = rsqrtf(deg[i] + 1.0f);
}
__global__ void linear2_kernel(const float* __restrict__ in, const float* __restrict__ acc,
                               const float* __restrict__ dinv, const float* __restrict__ W,
                               const float* __restrict__ bias, float* __restrict__ out,
                               int n, int mode) {
    __shared__ float Ws[F * F];
    __shared__ float As[16][F + 1];
    int t = threadIdx.x;
    Ws[t] = W[t];
    int nb = t >> 4, j = t & 15;
    int i = blockIdx.x * 16 + nb;
    float di = 0.f, v = 0.f;
    if (i < n) {
        di = dinv[i]; v = in[i * F + j];
        if (mode) { v = di * (acc[i * F + j] + v) + bias[j]; v = fmaxf(v, 0.f); }
    }
    As[nb][j] = v;
    __syncthreads();
    if (i < n) {
        float s = 0.f;
#pragma unroll
        for (int k = 0; k < F; ++k) s += As[nb][k] * Ws[k * F + j];
        out[i * F + j] = s * di;
    }
}
__global__ void scatter_kernel(const int* __restrict__ src, const int* __restrict__ dst,
                               const float* __restrict__ h, float* __restrict__ acc, int E) {
    int t = blockIdx.x * blockDim.x + threadIdx.x;
    int e = t >> 4, j = t & 15;
    if (e < E) atomicAdd(&acc[dst[e] * F + j], h[src[e] * F + j]);
}
__global__ void out_kernel(const float* __restrict__ acc, const float* __restrict__ h,
                           const float* __restrict__ dinv, const float* __restrict__ bias,
                           float* __restrict__ out, int n) {
    int t = blockIdx.x * blockDim.x + threadIdx.x;
    if (t < n * F) {
        int i = t >> 4, j = t & 15;
        out[t] = dinv[i] * (acc[t] + h[t]) + bias[j];
    }
}

// ========================= launch ===========================================

extern "C" void kernel_launch(void* const* d_in, const int* in_sizes, int n_in,
                              void* d_out, int out_size, void* d_ws, size_t ws_size,
                              hipStream_t stream) {
    const float* x  = (const float*)d_in[0];
    const int*   ei = (const int*)d_in[1];
    const float* W1 = (const float*)d_in[2];
    const float* b1 = (const float*)d_in[3];
    const float* W2 = (const float*)d_in[4];
    const float* b2 = (const float*)d_in[5];
    float* outp = (float*)d_out;

    const int N = in_sizes[0] / F;
    const int E = in_sizes[1] / 2;
    const int* src = ei;
    const int* dst = ei + E;

    const int nb_rt = (N + NPB - 1) >> BSHIFT;
    // ws layout (4B units): dinv[N] | hA[16N] | hB[16N] | recs[E] | srcs[E] |
    //                       noff[N+1] | bcount[NB] | off[NB+1] | cursor[16*NB]
    size_t need = sizeof(float) * ((size_t)N * 33 + (N + 1)
                                   + 2 * (size_t)E + NB + (NB + 1) + 16 * NB);

    if (nb_rt == NB && ws_size >= need) {
        float* dinv = (float*)d_ws;
        float* hA = dinv + N;
        float* hB = hA + (size_t)F * N;
        unsigned* recs = (unsigned*)(hB + (size_t)F * N);
        unsigned* srcs = recs + E;
        int* noff = (int*)(srcs + E);
        unsigned* bcount = (unsigned*)(noff + N + 1);
        int* off = (int*)(bcount + NB);
        unsigned* cursor = (unsigned*)(off + NB + 1);

        hipMemsetAsync(bcount, 0, NB * sizeof(unsigned), stream);
        hist_kernel<<<512, 256, 0, stream>>>(dst, bcount, E);
        scan_kernel<<<1, 1024, 0, stream>>>(bcount, off, cursor, E);
        reorder_kernel<<<(E + CH - 1) / CH, 512, 0, stream>>>(src, dst, cursor, recs, E);
        sort2_kernel<<<NB, 1024, 0, stream>>>(recs, off, srcs, noff, dinv, N, E);
        linear_kernel<<<(N + 63) / 64, 256, 0, stream>>>(x, dinv, W1, hA, N);
        agg_csr_kernel<<<(N + 63) / 64, 256, 0, stream>>>(hA, srcs, noff, dinv, W2, b1, hB, N, 1);
        agg_csr_kernel<<<(N + 63) / 64, 256, 0, stream>>>(hB, srcs, noff, dinv, nullptr, b2, outp, N, 2);
    } else {
        // R1 fallback: atomic scatter path (13.2MB ws)
        float* dinv = (float*)d_ws;
        float* h = dinv + N;
        float* acc = h + (size_t)F * N;
        hipMemsetAsync(dinv, 0, (size_t)N * sizeof(float), stream);
        hipMemsetAsync(acc, 0, (size_t)F * N * sizeof(float), stream);
        deg_kernel<<<(E + 255) / 256, 256, 0, stream>>>(dst, dinv, E);
        dinv_kernel<<<(N + 255) / 256, 256, 0, stream>>>(dinv, N);
        linear2_kernel<<<(N + 15) / 16, 256, 0, stream>>>(x, nullptr, dinv, W1, nullptr, h, N, 0);
        scatter_kernel<<<((size_t)E * F + 255) / 256, 256, 0, stream>>>(src, dst, h, acc, E);
        linear2_kernel<<<(N + 15) / 16, 256, 0, stream>>>(h, acc, dinv, W2, b1, h, N, 1);
        hipMemsetAsync(acc, 0, (size_t)F * N * sizeof(float), stream);
        scatter_kernel<<<((size_t)E * F + 255) / 256, 256, 0, stream>>>(src, dst, h, acc, E);
        out_kernel<<<((size_t)N * F + 255) / 256, 256, 0, stream>>>(acc, h, dinv, b2, outp, N);
    }
}